// Round 3
// baseline (93.509 us; speedup 1.0000x reference)
//
#include <hip/hip_runtime.h>
#include <math.h>

#define BSZ 4
#define NN  256
#define CC  96

#define XIN_OFF  0
#define EH_OFF   2048          // BSZ*NN*2
#define COV_OFF  100352        // 2048 + BSZ*NN*CC

#define INV_SQRT_2PI 0.3989422804014327f
#define EXP2C       -0.7213475204444817f   // -0.5*log2(e)
// Abramowitz-Stegun 7.1.25 (3-term, |erf err| <= 2.5e-5), arg pre-scaled by
// 1/sqrt2 (folded into P), 0.5 folded into the coefficients.
#define PHI_P   0.33267253f    // 0.47047/sqrt2
#define PHI_C1  0.1740121f     // 0.3480242*0.5
#define PHI_C2 -0.0479399f
#define PHI_C3  0.3739278f

typedef float        v2f __attribute__((ext_vector_type(2)));
typedef unsigned int v2u __attribute__((ext_vector_type(2)));

__device__ __forceinline__ v2f v2s(float s) { v2f r; r.x = s; r.y = s; return r; }

#if __has_builtin(__builtin_elementwise_fma)
#define V2FMA(a, b, c) __builtin_elementwise_fma((a), (b), (c))
#else
#define V2FMA(a, b, c) ((a) * (b) + (c))
#endif

__device__ __forceinline__ v2f v2_exp2(v2f x) {
    v2f r; r.x = __builtin_amdgcn_exp2f(x.x); r.y = __builtin_amdgcn_exp2f(x.y);
    return r;
}
__device__ __forceinline__ v2f v2_rcp(v2f x) {
    v2f r; r.x = __builtin_amdgcn_rcpf(x.x); r.y = __builtin_amdgcn_rcpf(x.y);
    return r;
}
__device__ __forceinline__ v2f v2_abs(v2f x) {
    v2u u = __builtin_bit_cast(v2u, x) & 0x7fffffffu;
    return __builtin_bit_cast(v2f, u);
}
// copysign(mag, sgn): mag known >= 0 here, still mask for safety -> v_bfi_b32
__device__ __forceinline__ v2f v2_copysign(v2f mag, v2f sgn) {
    v2u m = __builtin_bit_cast(v2u, mag) & 0x7fffffffu;
    v2u s = __builtin_bit_cast(v2u, sgn) & 0x80000000u;
    return __builtin_bit_cast(v2f, m | s);
}
// Phi(u) from e = exp(-u*u/2): 0.5 + copysign(0.5 - poly(t)*e, u)
__device__ __forceinline__ v2f v2_phi_from_exp(v2f u, v2f e) {
    v2f t  = v2_rcp(V2FMA(v2s(PHI_P), v2_abs(u), v2s(1.0f)));
    v2f hp = V2FMA(V2FMA(v2s(PHI_C3), t, v2s(PHI_C2)), t, v2s(PHI_C1)) * t * e;
    return v2s(0.5f) + v2_copysign(v2s(0.5f) - hp, u);
}

__device__ __forceinline__ float phi_from_exp_s(float u, float e) {
    float t  = __builtin_amdgcn_rcpf(__builtin_fmaf(PHI_P, fabsf(u), 1.0f));
    float hp = __builtin_fmaf(__builtin_fmaf(PHI_C3, t, PHI_C2), t, PHI_C1) * t * e;
    return 0.5f + __builtin_copysignf(0.5f - hp, u);
}

// One block per (b,i) row: Eh row, dvals -> diagonal of covar, xin copy.
__global__ __launch_bounds__(128) void relu_cov_row(
    const float* __restrict__ xin, const float* __restrict__ meanin,
    const float* __restrict__ kin, float* __restrict__ out)
{
    const int row = blockIdx.x;          // b*NN + i
    const int b   = row >> 8;
    const int i   = row & (NN - 1);
    const int tid = threadIdx.x;

    const float kd   = kin[((size_t)b * NN + i) * NN + i] + 1e-6f;
    const float var  = fmaxf(kd, 1e-8f);
    const float stdv = __builtin_amdgcn_sqrtf(var);
    const float rstd = __builtin_amdgcn_rcpf(stdv);

    float dterm = 0.0f;
    if (tid < CC) {
        float m  = meanin[(size_t)row * CC + tid];
        float z  = m * rstd;
        float e  = __builtin_amdgcn_exp2f(z * z * EXP2C);
        float ph = INV_SQRT_2PI * e;
        float Ph = phi_from_exp_s(z, e);
        float Eh = m * Ph + stdv * ph;
        out[EH_OFF + (size_t)row * CC + tid] = Eh;
        dterm = (m * m + var) * Ph + m * stdv * ph - Eh * Eh;
    } else if (tid < CC + 2) {
        int dd = tid - CC;                   // xin copy (d=2)
        out[XIN_OFF + (size_t)row * 2 + dd] = xin[(size_t)row * 2 + dd];
    }

    float v = dterm;
    v += __shfl_down(v, 32, 64);
    v += __shfl_down(v, 16, 64);
    v += __shfl_down(v,  8, 64);
    v += __shfl_down(v,  4, 64);
    v += __shfl_down(v,  2, 64);
    v += __shfl_down(v,  1, 64);
    __shared__ float wsum[2];
    if ((tid & 63) == 0) wsum[tid >> 6] = v;
    __syncthreads();
    if (tid == 0) {
        float dval = fmaxf((wsum[0] + wsum[1]) * (1.0f / 96.0f), 1e-6f);
        out[COV_OFF + ((size_t)b * NN + i) * NN + i] = dval + 1e-6f;
    }
}

// Pair kernel: block = (b*128+i2, ch). 256 threads, thread p = one pair of the
// balanced row-pair {i2, 255-i2}; each covers 24 c-values (chunk ch).
// Partial sums -> d_ws; no reduction, no atomics, no forced VGPR cap.
__global__ __launch_bounds__(256) void relu_cov_pair(
    const float* __restrict__ meanin, const float* __restrict__ kin,
    const float* __restrict__ Eh, float* __restrict__ partial)
{
    const int blk = blockIdx.x;     // b*128 + i2
    const int b   = blk >> 7;
    const int i2  = blk & 127;
    const int ch  = blockIdx.y;     // c-chunk 0..3
    const int p   = threadIdx.x;

    const int rowA = i2;
    const int rowB = 255 - i2;

    __shared__ __align__(16) float smA[24], sEA[24], smB[24], sEB[24];
    {
        const float* mA = meanin + ((size_t)(b * NN + rowA)) * CC + ch * 24;
        const float* eA = Eh     + ((size_t)(b * NN + rowA)) * CC + ch * 24;
        const float* mB = meanin + ((size_t)(b * NN + rowB)) * CC + ch * 24;
        const float* eB = Eh     + ((size_t)(b * NN + rowB)) * CC + ch * 24;
        if      (p < 24) smA[p]      = mA[p];
        else if (p < 48) sEA[p - 24] = eA[p - 24];
        else if (p < 72) smB[p - 48] = mB[p - 48];
        else if (p < 96) sEB[p - 72] = eB[p - 72];
    }
    __syncthreads();

    float* pout = partial + ((size_t)blk * 4 + ch) * 256 + p;
    if (p >= 255) { *pout = 0.0f; return; }

    const int  nfirst   = 255 - i2;
    const bool firstSeg = p < nfirst;
    const int  i = firstSeg ? rowA : rowB;
    const int  j = firstSeg ? (i2 + 1 + p) : (p + 1);

    const float* kb = kin + (size_t)b * NN * NN;
    const float m00 = kb[i * NN + i] + 1e-6f;
    const float m11 = kb[j * NN + j] + 1e-6f;
    const float m01 = 0.5f * (kb[i * NN + j] + kb[j * NN + i]);

    const float det = __builtin_fmaf(-m01, m01, m00 * m11);
    const float s   = __builtin_amdgcn_sqrtf(fmaxf(det, 1e-8f));
    const float t   = fmaxf(__builtin_amdgcn_sqrtf(m00 + m11 + 2.0f * s), 1e-8f);
    const float rt  = __builtin_amdgcn_rcpf(t);
    const float s00 = (m00 + s) * rt;
    const float s01 = m01 * rt;
    const float s11 = (m11 + s) * rt;
    const float dS  = fmaxf(__builtin_fmaf(-s01, s01, s00 * s11), 1e-8f);
    const float rdS = __builtin_amdgcn_rcpf(dS);
    const float i00 = s11 * rdS;
    const float i01 = -s01 * rdS;
    const float i11 = s00 * rdS;
    const float c0001   = s00 * s01;
    const float c0101_2 = 2.0f * s01 * s01;
    const float c0111   = s01 * s11;

    const float4* mjp = (const float4*)(meanin + ((size_t)(b * NN + j)) * CC + ch * 24);
    const float4* Ejp = (const float4*)(Eh     + ((size_t)(b * NN + j)) * CC + ch * 24);
    const float4* mip = (const float4*)(firstSeg ? smA : smB);
    const float4* Eip = (const float4*)(firstSeg ? sEA : sEB);

    v2f acc0 = v2s(0.0f), acc1 = v2s(0.0f);

    auto elem2 = [&](v2f mi, v2f mj, v2f Ei, v2f Ej) -> v2f {
        v2f u1 = V2FMA(mj, v2s(i01), mi * i00);
        v2f u2 = V2FMA(mj, v2s(i11), mi * i01);
        v2f e1 = v2_exp2(u1 * u1 * EXP2C);
        v2f e2 = v2_exp2(u2 * u2 * EXP2C);
        v2f Phi1 = v2_phi_from_exp(u1, e1);
        v2f Phi2 = v2_phi_from_exp(u2, e2);
        v2f p1 = e1 * INV_SQRT_2PI;
        v2f p2 = e2 * INV_SQRT_2PI;
        v2f a  = V2FMA(mi, mj, v2s(m01));                 // mi*mj + k_ij
        v2f bb = V2FMA(mi, v2s(s01), mj * s00);
        bb     = V2FMA(u1, v2s(-c0001), bb);
        v2f g1 = V2FMA(bb, p1, a * Phi1);
        v2f cc = V2FMA(mi, v2s(s11), mj * s01);
        cc     = V2FMA(u2, v2s(-c0111), cc);
        v2f r  = V2FMA(p1 * p2, v2s(c0101_2), Ei * (-Ej));
        r      = V2FMA(Phi1, cc * p2, r);
        r      = V2FMA(Phi2, g1, r);
        return r;
    };

#pragma unroll
    for (int q = 0; q < 6; ++q) {
        float4 mj4 = mjp[q];
        float4 Ej4 = Ejp[q];
        float4 mi4 = mip[q];
        float4 Ei4 = Eip[q];
        v2f miL = {mi4.x, mi4.y}, miH = {mi4.z, mi4.w};
        v2f mjL = {mj4.x, mj4.y}, mjH = {mj4.z, mj4.w};
        v2f EiL = {Ei4.x, Ei4.y}, EiH = {Ei4.z, Ei4.w};
        v2f EjL = {Ej4.x, Ej4.y}, EjH = {Ej4.z, Ej4.w};
        acc0 += elem2(miL, mjL, EiL, EjL);
        acc1 += elem2(miH, mjH, EiH, EjH);
    }

    v2f acc = acc0 + acc1;
    *pout = acc.x + acc.y;
}

// Combine the 4 c-chunk partials, scale, mirrored store (kin symmetric).
__global__ __launch_bounds__(256) void relu_cov_combine(
    const float* __restrict__ partial, float* __restrict__ out)
{
    const int blk = blockIdx.x;     // b*128 + i2
    const int b   = blk >> 7;
    const int i2  = blk & 127;
    const int p   = threadIdx.x;
    if (p >= 255) return;

    const float* base = partial + ((size_t)blk * 4) * 256 + p;
    float v = (base[0] + base[256] + base[512] + base[768]) * (1.0f / 96.0f);

    const int nfirst = 255 - i2;
    const int i = (p < nfirst) ? i2 : (255 - i2);
    const int j = (p < nfirst) ? (i2 + 1 + p) : (p + 1);
    out[COV_OFF + ((size_t)(b * NN + i)) * NN + j] = v;
    out[COV_OFF + ((size_t)(b * NN + j)) * NN + i] = v;
}

extern "C" void kernel_launch(void* const* d_in, const int* in_sizes, int n_in,
                              void* d_out, int out_size, void* d_ws, size_t ws_size,
                              hipStream_t stream) {
    const float* xin    = (const float*)d_in[0];
    const float* meanin = (const float*)d_in[1];
    const float* kin    = (const float*)d_in[2];
    float* out     = (float*)d_out;
    float* partial = (float*)d_ws;              // 512*4*256 floats = 2 MB

    relu_cov_row<<<BSZ * NN, 128, 0, stream>>>(xin, meanin, kin, out);
    relu_cov_pair<<<dim3(BSZ * 128, 4), 256, 0, stream>>>(
        meanin, kin, out + EH_OFF, partial);
    relu_cov_combine<<<BSZ * 128, 256, 0, stream>>>(partial, out);
}

// Round 4
// 85.101 us; speedup vs baseline: 1.0988x; 1.0988x over previous
//
#include <hip/hip_runtime.h>
#include <math.h>

#define BSZ 4
#define NN  256
#define CC  96

#define XIN_OFF  0
#define EH_OFF   2048          // BSZ*NN*2
#define COV_OFF  100352        // 2048 + BSZ*NN*CC

#define INV_SQRT_2PI 0.3989422804014327f
#define EXP2C       -0.7213475204444817f   // -0.5*log2(e)
// Abramowitz-Stegun 7.1.25 (3-term), arg pre-scaled by 1/sqrt2 (folded into
// P), 0.5 folded into the coefficients. Phi abs err ~1.3e-5.
#define PHI_P   0.33267253f
#define PHI_C1  0.1740121f
#define PHI_C2 -0.0479399f
#define PHI_C3  0.3739278f

__device__ __forceinline__ float phi_from_exp_s(float u, float e) {
    float t  = __builtin_amdgcn_rcpf(__builtin_fmaf(PHI_P, fabsf(u), 1.0f));
    float hp = __builtin_fmaf(__builtin_fmaf(PHI_C3, t, PHI_C2), t, PHI_C1) * t * e;
    return 0.5f + __builtin_copysignf(0.5f - hp, u);
}

// One block per (b,i) row: Eh row, dvals -> diagonal of covar, xin copy.
__global__ __launch_bounds__(128) void relu_cov_row(
    const float* __restrict__ xin, const float* __restrict__ meanin,
    const float* __restrict__ kin, float* __restrict__ out)
{
    const int row = blockIdx.x;          // b*NN + i
    const int b   = row >> 8;
    const int i   = row & (NN - 1);
    const int tid = threadIdx.x;

    const float kd   = kin[((size_t)b * NN + i) * NN + i] + 1e-6f;
    const float var  = fmaxf(kd, 1e-8f);
    const float stdv = __builtin_amdgcn_sqrtf(var);
    const float rstd = __builtin_amdgcn_rcpf(stdv);

    float dterm = 0.0f;
    if (tid < CC) {
        float m  = meanin[(size_t)row * CC + tid];
        float z  = m * rstd;
        float e  = __builtin_amdgcn_exp2f(z * z * EXP2C);
        float ph = INV_SQRT_2PI * e;
        float Ph = phi_from_exp_s(z, e);
        float Eh = m * Ph + stdv * ph;
        out[EH_OFF + (size_t)row * CC + tid] = Eh;
        dterm = (m * m + var) * Ph + m * stdv * ph - Eh * Eh;
    } else if (tid < CC + 2) {
        int dd = tid - CC;                   // xin copy (d=2)
        out[XIN_OFF + (size_t)row * 2 + dd] = xin[(size_t)row * 2 + dd];
    }

    float v = dterm;
    v += __shfl_down(v, 32, 64);
    v += __shfl_down(v, 16, 64);
    v += __shfl_down(v,  8, 64);
    v += __shfl_down(v,  4, 64);
    v += __shfl_down(v,  2, 64);
    v += __shfl_down(v,  1, 64);
    __shared__ float wsum[2];
    if ((tid & 63) == 0) wsum[tid >> 6] = v;
    __syncthreads();
    if (tid == 0) {
        float dval = fmaxf((wsum[0] + wsum[1]) * (1.0f / 96.0f), 1e-6f);
        out[COV_OFF + ((size_t)b * NN + i) * NN + i] = dval + 1e-6f;
    }
}

// Pair kernel. Block = (b, i2): the 255 upper-triangle pairs of balanced
// row-pair {i2, 255-i2}. 512 threads: pair p = tid&255, c-half h = tid>>8
// (48 c's each). LDS reduce the two halves, mirrored store (kin exactly
// symmetric => covar symmetric, and m10 == m01 so m10 is never loaded).
__global__ __launch_bounds__(512, 4) void relu_cov_pair(
    const float* __restrict__ meanin, const float* __restrict__ kin,
    const float* __restrict__ Eh, float* __restrict__ out)
{
    const int blk = blockIdx.x;     // b*128 + i2
    const int b   = blk >> 7;
    const int i2  = blk & 127;
    const int tid = threadIdx.x;
    const int p   = tid & 255;
    const int h   = tid >> 8;       // c-half 0/1

    const int rowA = i2;
    const int rowB = 255 - i2;

    __shared__ __align__(16) float smA[CC], sEA[CC], smB[CC], sEB[CC];
    __shared__ float red[512];
    {
        const float* mA = meanin + ((size_t)(b * NN + rowA)) * CC;
        const float* eA = Eh     + ((size_t)(b * NN + rowA)) * CC;
        const float* mB = meanin + ((size_t)(b * NN + rowB)) * CC;
        const float* eB = Eh     + ((size_t)(b * NN + rowB)) * CC;
        if      (tid < 96)  smA[tid]       = mA[tid];
        else if (tid < 192) sEA[tid - 96]  = eA[tid - 96];
        else if (tid < 288) smB[tid - 192] = mB[tid - 192];
        else if (tid < 384) sEB[tid - 288] = eB[tid - 288];
    }
    __syncthreads();

    float acc0 = 0.0f, acc1 = 0.0f;
    if (p < 255) {
        const int  nfirst   = 255 - i2;
        const bool firstSeg = p < nfirst;
        const int  i = firstSeg ? rowA : rowB;
        const int  j = firstSeg ? (i2 + 1 + p) : (p + 1);

        const float* kb  = kin + (size_t)b * NN * NN;
        const float  m00 = kb[i * (NN + 1)] + 1e-6f;
        const float  m11 = kb[j * (NN + 1)] + 1e-6f;
        const float  m01 = kb[i * NN + j];          // == m10 exactly

        const float det = __builtin_fmaf(-m01, m01, m00 * m11);
        const float s   = __builtin_amdgcn_sqrtf(fmaxf(det, 1e-8f));
        const float t   = fmaxf(__builtin_amdgcn_sqrtf(m00 + m11 + 2.0f * s), 1e-8f);
        const float rt  = __builtin_amdgcn_rcpf(t);
        const float s00 = (m00 + s) * rt;
        const float s01 = m01 * rt;
        const float s11 = (m11 + s) * rt;
        const float dS  = fmaxf(__builtin_fmaf(-s01, s01, s00 * s11), 1e-8f);
        const float rdS = __builtin_amdgcn_rcpf(dS);
        const float i00 = s11 * rdS;
        const float i01 = -s01 * rdS;
        const float i11 = s00 * rdS;
        // psi-bracket coefficients collapse (see header comment):
        //   mj*s00 + mi*s01 - s00*s01*u1 = (qj*mj + qd*mi)
        //   mj*s01 + mi*s11 - s01*s11*u2 = (qd*mj + qi*mi)
        const float qd = -s01 * s01 * s01 * rdS;
        const float qj = s00 * s00 * s11 * rdS;
        const float qi = s00 * s11 * s11 * rdS;
        const float c2 = 2.0f * s01 * s01;

        const float4* mjp = (const float4*)(meanin + ((size_t)(b * NN + j)) * CC + h * 48);
        const float4* Ejp = (const float4*)(Eh     + ((size_t)(b * NN + j)) * CC + h * 48);
        const float4* mip = (const float4*)((firstSeg ? smA : smB) + h * 48);
        const float4* Eip = (const float4*)((firstSeg ? sEA : sEB) + h * 48);

        auto elem = [&](float mi, float mjv, float Ei, float Ej, float& acc) {
            float u1 = __builtin_fmaf(i01, mjv, i00 * mi);
            float u2 = __builtin_fmaf(i11, mjv, i01 * mi);
            float e1 = __builtin_amdgcn_exp2f(u1 * u1 * EXP2C);
            float e2 = __builtin_amdgcn_exp2f(u2 * u2 * EXP2C);
            float d1 = __builtin_fmaf(PHI_P, fabsf(u1), 1.0f);
            float d2 = __builtin_fmaf(PHI_P, fabsf(u2), 1.0f);
            float rp = __builtin_amdgcn_rcpf(d1 * d2);   // shared rcp
            float t1 = d2 * rp;
            float t2 = d1 * rp;
            float hp1 = __builtin_fmaf(__builtin_fmaf(PHI_C3, t1, PHI_C2), t1, PHI_C1) * t1 * e1;
            float hp2 = __builtin_fmaf(__builtin_fmaf(PHI_C3, t2, PHI_C2), t2, PHI_C1) * t2 * e2;
            float Phi1 = 0.5f + __builtin_copysignf(0.5f - hp1, u1);
            float Phi2 = 0.5f + __builtin_copysignf(0.5f - hp2, u2);
            float p1 = INV_SQRT_2PI * e1;
            float p2 = INV_SQRT_2PI * e2;
            float a  = __builtin_fmaf(mi, mjv, m01);
            float bb = __builtin_fmaf(qd, mi, qj * mjv);
            float cc = __builtin_fmaf(qi, mi, qd * mjv);
            acc = __builtin_fmaf(a,  Phi1 * Phi2, acc);
            acc = __builtin_fmaf(bb, p1 * Phi2,  acc);
            acc = __builtin_fmaf(cc, Phi1 * p2,  acc);
            acc = __builtin_fmaf(c2, p1 * p2,    acc);
            acc = __builtin_fmaf(-Ei, Ej,        acc);
        };

#pragma unroll 3
        for (int q = 0; q < 12; ++q) {
            float4 mj4 = mjp[q];
            float4 Ej4 = Ejp[q];
            float4 mi4 = mip[q];
            float4 Ei4 = Eip[q];
            elem(mi4.x, mj4.x, Ei4.x, Ej4.x, acc0);
            elem(mi4.y, mj4.y, Ei4.y, Ej4.y, acc1);
            elem(mi4.z, mj4.z, Ei4.z, Ej4.z, acc0);
            elem(mi4.w, mj4.w, Ei4.w, Ej4.w, acc1);
        }
    }

    red[tid] = acc0 + acc1;
    __syncthreads();

    if (tid < 255) {
        float v = (red[tid] + red[tid + 256]) * (1.0f / 96.0f);
        const int nfirst = 255 - i2;
        const int i = (tid < nfirst) ? i2 : (255 - i2);
        const int j = (tid < nfirst) ? (i2 + 1 + tid) : (tid + 1);
        out[COV_OFF + ((size_t)(b * NN + i)) * NN + j] = v;
        out[COV_OFF + ((size_t)(b * NN + j)) * NN + i] = v;
    }
}

extern "C" void kernel_launch(void* const* d_in, const int* in_sizes, int n_in,
                              void* d_out, int out_size, void* d_ws, size_t ws_size,
                              hipStream_t stream) {
    const float* xin    = (const float*)d_in[0];
    const float* meanin = (const float*)d_in[1];
    const float* kin    = (const float*)d_in[2];
    float* out = (float*)d_out;

    relu_cov_row<<<BSZ * NN, 128, 0, stream>>>(xin, meanin, kin, out);
    relu_cov_pair<<<BSZ * 128, 512, 0, stream>>>(meanin, kin, out + EH_OFF, out);
}